// Round 4
// baseline (3044.957 us; speedup 1.0000x reference)
//
#include <hip/hip_runtime.h>

// R7 -> R8: THE LAW (fits R4/R5/R7 + fallback quantitatively): LDS f32
// atomicAdd retires ~1 LANE per 3.5 cy on the CU's single LDS pipe (~220
// cy per wave64 ds_add). Accum kernels all ran at their lane-atomic count
// x3.5cy/256CU regardless of gathers/banking/MLP. Fix: ATOMIC-FREE accum.
//   - sort tuples to 64-atom bins (nbins=3125): one WAVE per bin, one
//     ATOM per LANE. Wave streams its bin (uniform addr -> 1 req/load),
//     lane does predicated FMA into 4 VGPRs. No LDS, no atomics, direct
//     coalesced float4 store (k_final eliminated).
//   - hist/scatter keep 2 LDS atomics/edge each (known ~146us tax) --
//     attack next if accum lands.
// ws: tuples 205MB + chist/coffs 2x6.4MB + ctot/cbase -> ~218MB (fits).

#define NCH    512          // edge chunks for hist/scatter
#define TB     1024         // hist/scatter block size
#define BINLOG 6
#define MAXB   4096         // max bins (LDS hist 16 KB)
#define WPB    4            // waves per accum block (256 threads)

static __device__ __forceinline__ unsigned long long nt_u64(const void* p) {
    return __builtin_nontemporal_load((const unsigned long long*)p);
}
static __device__ __forceinline__ float nt_f32(const float* p) {
    return __builtin_nontemporal_load(p);
}
static __device__ __forceinline__ void nt_st_u64(unsigned long long v, void* p) {
    __builtin_nontemporal_store(v, (unsigned long long*)p);
}

// ---- G1: per-chunk histogram over 64-atom bins (both endpoints) ---------
__global__ __launch_bounds__(TB) void g_hist(
    const int2* __restrict__ nbr, int* __restrict__ chist,
    int n_edges, int nbins)
{
    __shared__ int h[MAXB];
    for (int i = threadIdx.x; i < nbins; i += TB) h[i] = 0;
    __syncthreads();
    int per = (n_edges + NCH - 1) / NCH;
    int lo = blockIdx.x * per;
    int hi = min(lo + per, n_edges);
    #pragma unroll 2
    for (int e = lo + threadIdx.x; e < hi; e += TB) {
        unsigned long long v = nt_u64(&nbr[e]);
        int ix = (int)(v & 0xffffffffu);
        int iy = (int)(v >> 32);
        atomicAdd(&h[ix >> BINLOG], 1);
        atomicAdd(&h[iy >> BINLOG], 1);
    }
    __syncthreads();
    int* out = chist + (size_t)blockIdx.x * nbins;
    for (int i = threadIdx.x; i < nbins; i += TB) out[i] = h[i];
}

// ---- G2: scan each bin's NCH chunk-counts -------------------------------
__global__ __launch_bounds__(NCH) void g_rowscan(
    const int* __restrict__ chist, int* __restrict__ coffs,
    int* __restrict__ ctot, int nbins)
{
    __shared__ int a[NCH];
    int bin = blockIdx.x, t = threadIdx.x;
    int v = chist[(size_t)t * nbins + bin];
    a[t] = v;
    __syncthreads();
    for (int off = 1; off < NCH; off <<= 1) {
        int x = (t >= off) ? a[t - off] : 0;
        __syncthreads();
        a[t] += x;
        __syncthreads();
    }
    coffs[(size_t)t * nbins + bin] = a[t] - v;
    if (t == NCH - 1) ctot[bin] = a[t];
}

// ---- G3: exclusive scan of bin totals (one block, items<=8) -------------
__global__ __launch_bounds__(1024) void g_bases(
    const int* __restrict__ ctot, int* __restrict__ cbase, int nbins)
{
    __shared__ int sums[1024];
    int t = threadIdx.x;
    int items = (nbins + 1023) >> 10;      // 4 for nbins=3125
    int v[8];
    int run = 0;
    #pragma unroll
    for (int k = 0; k < 8; ++k) {
        if (k < items) {
            int idx = t * items + k;
            int x = (idx < nbins) ? ctot[idx] : 0;
            v[k] = run; run += x;
        }
    }
    sums[t] = run;
    __syncthreads();
    for (int off = 1; off < 1024; off <<= 1) {
        int x = (t >= off) ? sums[t - off] : 0;
        __syncthreads();
        sums[t] += x;
        __syncthreads();
    }
    int prefix = (t == 0) ? 0 : sums[t - 1];
    #pragma unroll
    for (int k = 0; k < 8; ++k) {
        if (k < items) {
            int idx = t * items + k;
            if (idx < nbins) cbase[idx] = prefix + v[k];
        }
    }
}

// ---- G4: coffs[chunk][bin] += cbase[bin] --------------------------------
__global__ __launch_bounds__(1024) void g_addbase(
    int* __restrict__ coffs, const int* __restrict__ cbase, int nbins)
{
    int bin = blockIdx.x * 1024 + threadIdx.x;
    if (bin < nbins)
        coffs[(size_t)blockIdx.y * nbins + bin] += cbase[bin];
}

// ---- G5: scatter TWO tuples per edge into dst bins ----------------------
// tuple.x = dst_lane(6b) | src_global(18b)<<6 ; tuple.y = w bits
__global__ __launch_bounds__(TB) void g_scatter(
    const int2* __restrict__ nbr, const float* __restrict__ dist,
    const int* __restrict__ coffs, uint2* __restrict__ tuples,
    int n_edges, int nbins)
{
    __shared__ int cur[MAXB];
    const int* src = coffs + (size_t)blockIdx.x * nbins;
    for (int i = threadIdx.x; i < nbins; i += TB) cur[i] = src[i];
    __syncthreads();
    int per = (n_edges + NCH - 1) / NCH;
    int lo = blockIdx.x * per;
    int hi = min(lo + per, n_edges);
    #pragma unroll 2
    for (int e = lo + threadIdx.x; e < hi; e += TB) {
        unsigned long long v = nt_u64(&nbr[e]);
        int ix = (int)(v & 0xffffffffu);
        int iy = (int)(v >> 32);
        float w = 0.5f / nt_f32(&dist[e]);
        unsigned wb = __float_as_uint(w);
        int pi = atomicAdd(&cur[ix >> BINLOG], 1);
        nt_st_u64((unsigned long long)((unsigned)(ix & 63) | ((unsigned)iy << 6))
                  | ((unsigned long long)wb << 32), &tuples[pi]);
        int pj = atomicAdd(&cur[iy >> BINLOG], 1);
        nt_st_u64((unsigned long long)((unsigned)(iy & 63) | ((unsigned)ix << 6))
                  | ((unsigned long long)wb << 32), &tuples[pj]);
    }
}

// ---- G6: atomic-free accumulation: one wave per bin, one atom per lane --
__global__ __launch_bounds__(64 * WPB) void g_accum(
    const uint2* __restrict__ tuples, const float4* __restrict__ charges,
    const int* __restrict__ cbase, const int* __restrict__ ctot,
    float4* __restrict__ out, int nbins, int n_atoms)
{
    int wave = blockIdx.x * WPB + (threadIdx.x >> 6);
    if (wave >= nbins) return;
    int lane = threadIdx.x & 63;
    int lo = cbase[wave];
    int hi = lo + ctot[wave];
    float ax = 0.f, ay = 0.f, az = 0.f, aw = 0.f;

    int p = lo;
    for (; p + 7 < hi; p += 8) {
        unsigned long long t[8];
        float4 c[8];
        #pragma unroll
        for (int k = 0; k < 8; ++k) t[k] = nt_u64(&tuples[p + k]);
        #pragma unroll
        for (int k = 0; k < 8; ++k)
            c[k] = charges[(unsigned)(t[k] & 0xffffffffu) >> 6];
        #pragma unroll
        for (int k = 0; k < 8; ++k) {
            unsigned x = (unsigned)(t[k] & 0xffffffffu);
            float ws = ((int)(x & 63) == lane)
                       ? __uint_as_float((unsigned)(t[k] >> 32)) : 0.f;
            ax += c[k].x * ws; ay += c[k].y * ws;
            az += c[k].z * ws; aw += c[k].w * ws;
        }
    }
    for (; p < hi; ++p) {
        unsigned long long t = nt_u64(&tuples[p]);
        unsigned x = (unsigned)(t & 0xffffffffu);
        float4 c = charges[x >> 6];
        float ws = ((int)(x & 63) == lane)
                   ? __uint_as_float((unsigned)(t >> 32)) : 0.f;
        ax += c.x * ws; ay += c.y * ws; az += c.z * ws; aw += c.w * ws;
    }
    int a = (wave << BINLOG) + lane;
    if (a < n_atoms) out[a] = make_float4(ax, ay, az, aw);
}

// ---- fallback (ws too small / bins too many): agent-scope atomics -------
__global__ __launch_bounds__(256) void edge_scatter_agent(
    const float4* __restrict__ charges, const int2* __restrict__ nbr,
    const float* __restrict__ dist, float* __restrict__ out, int n_edges)
{
    int e = blockIdx.x * blockDim.x + threadIdx.x;
    if (e >= n_edges) return;
    int2 ij = nbr[e];
    float w = 0.5f / dist[e];
    float4 cj = charges[ij.y];
    float4 ci = charges[ij.x];
    float* oi = out + (size_t)ij.x * 4;
    float* oj = out + (size_t)ij.y * 4;
    atomicAdd(oi + 0, cj.x * w); atomicAdd(oi + 1, cj.y * w);
    atomicAdd(oi + 2, cj.z * w); atomicAdd(oi + 3, cj.w * w);
    atomicAdd(oj + 0, ci.x * w); atomicAdd(oj + 1, ci.y * w);
    atomicAdd(oj + 2, ci.z * w); atomicAdd(oj + 3, ci.w * w);
}

// ============================== launcher =================================

extern "C" void kernel_launch(void* const* d_in, const int* in_sizes, int n_in,
                              void* d_out, int out_size, void* d_ws, size_t ws_size,
                              hipStream_t stream)
{
    const float4* charges = (const float4*)d_in[0];
    const int2*   nbr     = (const int2*)d_in[3];
    const float*  dist    = (const float*)d_in[4];

    int n_edges = in_sizes[4];
    int n_atoms = out_size / 4;
    int nbins   = (n_atoms + 63) >> BINLOG;     // 3125 for 200000 atoms

    char* w = (char*)d_ws;
    auto align256 = [](size_t x) { return (x + 255) & ~(size_t)255; };

    size_t n_tup = (size_t)2 * n_edges;
    size_t szT = n_tup * sizeof(uint2);                  // ~205 MB
    size_t szH = (size_t)NCH * nbins * sizeof(int);      // ~6.4 MB

    size_t off = 0;
    size_t oT  = off; off += align256(szT);
    size_t oCH = off; off += align256(szH);
    size_t oCO = off; off += align256(szH);
    size_t oCT = off; off += align256((size_t)nbins * sizeof(int));
    size_t oCB = off; off += align256((size_t)nbins * sizeof(int));
    bool ok = (off <= ws_size) && (nbins <= MAXB);

    if (ok) {
        uint2* tuples = (uint2*)(w + oT);
        int*   chist  = (int*)(w + oCH);
        int*   coffs  = (int*)(w + oCO);
        int*   ctot   = (int*)(w + oCT);
        int*   cbase  = (int*)(w + oCB);

        g_hist   <<<NCH, TB, 0, stream>>>(nbr, chist, n_edges, nbins);
        g_rowscan<<<nbins, NCH, 0, stream>>>(chist, coffs, ctot, nbins);
        g_bases  <<<1, 1024, 0, stream>>>(ctot, cbase, nbins);
        {
            dim3 g((nbins + 1023) / 1024, NCH);
            g_addbase<<<g, 1024, 0, stream>>>(coffs, cbase, nbins);
        }
        g_scatter<<<NCH, TB, 0, stream>>>(nbr, dist, coffs, tuples,
                                          n_edges, nbins);
        g_accum  <<<(nbins + WPB - 1) / WPB, 64 * WPB, 0, stream>>>(
            tuples, charges, cbase, ctot, (float4*)d_out, nbins, n_atoms);
    } else {
        hipMemsetAsync(d_out, 0, (size_t)out_size * sizeof(float), stream);
        edge_scatter_agent<<<(n_edges + 255) / 256, 256, 0, stream>>>(
            charges, nbr, dist, (float*)d_out, n_edges);
    }
}

// Round 5
// 1669.005 us; speedup vs baseline: 1.8244x; 1.8244x over previous
//
#include <hip/hip_runtime.h>

// R8 -> R9: R8's wave-per-bin serialized (64x issue redundancy, 1735us,
// VALUBusy 20%) -- design error, law untested. Law status: R5 (atomics +
// gathers) == R7 (atomics, NO gathers) ~= 3.3 cy per LDS-ATOMIC lane-op;
// gather theory refuted by R7. R9 removes atomics from accumulation:
//   - 16-atom bins (12500), counting sort as before (NCH=256 chunks).
//   - n_accum: thread-private LDS accumulators, layout [d][tid] (d*4096B
//     + tid*16B = canonical conflict-free f4 pattern). Thread owns one
//     (bin,slice) tuple slice -> single-writer -> plain b128 RMW, ZERO
//     atomics. 16 bins x 16 slices per 256-thr block; in-block reduce
//     writes out directly (no partials/k_final).
//   - charge gather kept (L2-resident) as ablation: if accum still ~550us
//     the law is scattered-VMEM, not LDS atomics -> carry payloads next.
// ws: 205MB tuples + 2x12.8MB hist/offs + 2x50KB -> ~231MB.

#define NCH    256          // edge chunks for hist/scatter
#define TB     1024         // hist/scatter block size
#define BINLOG 4
#define BINSZ  16
#define MAXB   12544        // max bins (LDS hist 50 KB)
#define SLICES 16

static __device__ __forceinline__ unsigned long long nt_u64(const void* p) {
    return __builtin_nontemporal_load((const unsigned long long*)p);
}
static __device__ __forceinline__ float nt_f32(const float* p) {
    return __builtin_nontemporal_load(p);
}
static __device__ __forceinline__ void nt_st_u64(unsigned long long v, void* p) {
    __builtin_nontemporal_store(v, (unsigned long long*)p);
}

// ---- N1: per-chunk histogram over 16-atom bins (both endpoints) ---------
__global__ __launch_bounds__(TB) void n_hist(
    const int2* __restrict__ nbr, int* __restrict__ chist,
    int n_edges, int nbins)
{
    __shared__ int h[MAXB];
    for (int i = threadIdx.x; i < nbins; i += TB) h[i] = 0;
    __syncthreads();
    int per = (n_edges + NCH - 1) / NCH;
    int lo = blockIdx.x * per;
    int hi = min(lo + per, n_edges);
    #pragma unroll 2
    for (int e = lo + threadIdx.x; e < hi; e += TB) {
        unsigned long long v = nt_u64(&nbr[e]);
        int ix = (int)(v & 0xffffffffu);
        int iy = (int)(v >> 32);
        atomicAdd(&h[ix >> BINLOG], 1);
        atomicAdd(&h[iy >> BINLOG], 1);
    }
    __syncthreads();
    int* out = chist + (size_t)blockIdx.x * nbins;
    for (int i = threadIdx.x; i < nbins; i += TB) out[i] = h[i];
}

// ---- N2: scan each bin's NCH chunk-counts -------------------------------
__global__ __launch_bounds__(NCH) void n_rowscan(
    const int* __restrict__ chist, int* __restrict__ coffs,
    int* __restrict__ ctot, int nbins)
{
    __shared__ int a[NCH];
    int bin = blockIdx.x, t = threadIdx.x;
    int v = chist[(size_t)t * nbins + bin];
    a[t] = v;
    __syncthreads();
    for (int off = 1; off < NCH; off <<= 1) {
        int x = (t >= off) ? a[t - off] : 0;
        __syncthreads();
        a[t] += x;
        __syncthreads();
    }
    coffs[(size_t)t * nbins + bin] = a[t] - v;
    if (t == NCH - 1) ctot[bin] = a[t];
}

// ---- N3: exclusive scan of bin totals (one block) -----------------------
__global__ __launch_bounds__(1024) void n_bases(
    const int* __restrict__ ctot, int* __restrict__ cbase, int nbins)
{
    __shared__ int sums[1024];
    int t = threadIdx.x;
    int items = (nbins + 1023) >> 10;      // 13 for nbins=12500
    int v[16];
    int run = 0;
    #pragma unroll
    for (int k = 0; k < 16; ++k) {
        if (k < items) {
            int idx = t * items + k;
            int x = (idx < nbins) ? ctot[idx] : 0;
            v[k] = run; run += x;
        }
    }
    sums[t] = run;
    __syncthreads();
    for (int off = 1; off < 1024; off <<= 1) {
        int x = (t >= off) ? sums[t - off] : 0;
        __syncthreads();
        sums[t] += x;
        __syncthreads();
    }
    int prefix = (t == 0) ? 0 : sums[t - 1];
    #pragma unroll
    for (int k = 0; k < 16; ++k) {
        if (k < items) {
            int idx = t * items + k;
            if (idx < nbins) cbase[idx] = prefix + v[k];
        }
    }
}

// ---- N4: coffs[chunk][bin] += cbase[bin] --------------------------------
__global__ __launch_bounds__(1024) void n_addbase(
    int* __restrict__ coffs, const int* __restrict__ cbase, int nbins)
{
    int bin = blockIdx.x * 1024 + threadIdx.x;
    if (bin < nbins)
        coffs[(size_t)blockIdx.y * nbins + bin] += cbase[bin];
}

// ---- N5: scatter TWO tuples per edge into dst bins ----------------------
// tuple.x = dst_local(4b) | src_global(18b)<<4 ; tuple.y = w bits
__global__ __launch_bounds__(TB) void n_scatter(
    const int2* __restrict__ nbr, const float* __restrict__ dist,
    const int* __restrict__ coffs, uint2* __restrict__ tuples,
    int n_edges, int nbins)
{
    __shared__ int cur[MAXB];
    const int* src = coffs + (size_t)blockIdx.x * nbins;
    for (int i = threadIdx.x; i < nbins; i += TB) cur[i] = src[i];
    __syncthreads();
    int per = (n_edges + NCH - 1) / NCH;
    int lo = blockIdx.x * per;
    int hi = min(lo + per, n_edges);
    #pragma unroll 2
    for (int e = lo + threadIdx.x; e < hi; e += TB) {
        unsigned long long v = nt_u64(&nbr[e]);
        int ix = (int)(v & 0xffffffffu);
        int iy = (int)(v >> 32);
        float w = 0.5f / nt_f32(&dist[e]);
        unsigned wb = __float_as_uint(w);
        int pi = atomicAdd(&cur[ix >> BINLOG], 1);
        nt_st_u64((unsigned long long)((unsigned)(ix & (BINSZ - 1)) | ((unsigned)iy << BINLOG))
                  | ((unsigned long long)wb << 32), &tuples[pi]);
        int pj = atomicAdd(&cur[iy >> BINLOG], 1);
        nt_st_u64((unsigned long long)((unsigned)(iy & (BINSZ - 1)) | ((unsigned)ix << BINLOG))
                  | ((unsigned long long)wb << 32), &tuples[pj]);
    }
}

// ---- N6: atomic-free accumulation: thread-private LDS, conflict-free ----
// block = 256 thr = 16 bins x 16 slices; thread t: bin = blk*16 + t/16,
// slice = t%16. Private acc slot for (d, t) at accv[d*256 + t].
__global__ __launch_bounds__(256) void n_accum(
    const uint2* __restrict__ tuples, const float4* __restrict__ charges,
    const int* __restrict__ cbase, const int* __restrict__ ctot,
    float4* __restrict__ out, int nbins, int n_atoms)
{
    __shared__ float4 accv[BINSZ * 256];   // 64 KB
    int tid = threadIdx.x;
    float4 z = make_float4(0.f, 0.f, 0.f, 0.f);
    #pragma unroll
    for (int d = 0; d < BINSZ; ++d) accv[d * 256 + tid] = z;   // own slots

    int bin = blockIdx.x * 16 + (tid >> 4);
    int sl  = tid & 15;
    if (bin < nbins) {
        int lo = cbase[bin], cnt = ctot[bin];
        int s = lo + (int)((long long)cnt * sl / SLICES);
        int e = lo + (int)((long long)cnt * (sl + 1) / SLICES);

        int p = s;
        for (; p + 8 <= e; p += 8) {
            unsigned long long t0 = nt_u64(&tuples[p + 0]);
            unsigned long long t1 = nt_u64(&tuples[p + 1]);
            unsigned long long t2 = nt_u64(&tuples[p + 2]);
            unsigned long long t3 = nt_u64(&tuples[p + 3]);
            unsigned long long t4 = nt_u64(&tuples[p + 4]);
            unsigned long long t5 = nt_u64(&tuples[p + 5]);
            unsigned long long t6 = nt_u64(&tuples[p + 6]);
            unsigned long long t7 = nt_u64(&tuples[p + 7]);
            __builtin_amdgcn_sched_barrier(0);
            float4 c0 = charges[(unsigned)t0 >> BINLOG];
            float4 c1 = charges[(unsigned)t1 >> BINLOG];
            float4 c2 = charges[(unsigned)t2 >> BINLOG];
            float4 c3 = charges[(unsigned)t3 >> BINLOG];
            float4 c4 = charges[(unsigned)t4 >> BINLOG];
            float4 c5 = charges[(unsigned)t5 >> BINLOG];
            float4 c6 = charges[(unsigned)t6 >> BINLOG];
            float4 c7 = charges[(unsigned)t7 >> BINLOG];
            __builtin_amdgcn_sched_barrier(0);
            #define ACC1(T, C) { \
                unsigned x_ = (unsigned)(T); \
                float w_ = __uint_as_float((unsigned)((T) >> 32)); \
                int idx_ = (int)(x_ & (BINSZ - 1)) * 256 + tid; \
                float4 v_ = accv[idx_]; \
                v_.x += (C).x * w_; v_.y += (C).y * w_; \
                v_.z += (C).z * w_; v_.w += (C).w * w_; \
                accv[idx_] = v_; }
            ACC1(t0, c0) ACC1(t1, c1) ACC1(t2, c2) ACC1(t3, c3)
            ACC1(t4, c4) ACC1(t5, c5) ACC1(t6, c6) ACC1(t7, c7)
        }
        for (; p < e; ++p) {
            unsigned long long t = nt_u64(&tuples[p]);
            float4 c = charges[(unsigned)t >> BINLOG];
            ACC1(t, c)
            #undef ACC1
        }
    }
    __syncthreads();

    // reduce 16 slice-copies: thread handles atom (binL = tid/16, d = tid%16)
    int binL = tid >> 4, d = tid & 15;
    int bin2 = blockIdx.x * 16 + binL;
    int a = (bin2 << BINLOG) | d;
    if (bin2 < nbins && a < n_atoms) {
        float4 r = z;
        #pragma unroll
        for (int s2 = 0; s2 < SLICES; ++s2) {
            float4 v = accv[d * 256 + binL * 16 + s2];
            r.x += v.x; r.y += v.y; r.z += v.z; r.w += v.w;
        }
        out[a] = r;
    }
}

// ---- fallback (ws too small / bins too many): agent-scope atomics -------
__global__ __launch_bounds__(256) void edge_scatter_agent(
    const float4* __restrict__ charges, const int2* __restrict__ nbr,
    const float* __restrict__ dist, float* __restrict__ out, int n_edges)
{
    int e = blockIdx.x * blockDim.x + threadIdx.x;
    if (e >= n_edges) return;
    int2 ij = nbr[e];
    float w = 0.5f / dist[e];
    float4 cj = charges[ij.y];
    float4 ci = charges[ij.x];
    float* oi = out + (size_t)ij.x * 4;
    float* oj = out + (size_t)ij.y * 4;
    atomicAdd(oi + 0, cj.x * w); atomicAdd(oi + 1, cj.y * w);
    atomicAdd(oi + 2, cj.z * w); atomicAdd(oi + 3, cj.w * w);
    atomicAdd(oj + 0, ci.x * w); atomicAdd(oj + 1, ci.y * w);
    atomicAdd(oj + 2, ci.z * w); atomicAdd(oj + 3, ci.w * w);
}

// ============================== launcher =================================

extern "C" void kernel_launch(void* const* d_in, const int* in_sizes, int n_in,
                              void* d_out, int out_size, void* d_ws, size_t ws_size,
                              hipStream_t stream)
{
    const float4* charges = (const float4*)d_in[0];
    const int2*   nbr     = (const int2*)d_in[3];
    const float*  dist    = (const float*)d_in[4];

    int n_edges = in_sizes[4];
    int n_atoms = out_size / 4;
    int nbins   = (n_atoms + BINSZ - 1) >> BINLOG;   // 12500 for 200000 atoms

    char* w = (char*)d_ws;
    auto align256 = [](size_t x) { return (x + 255) & ~(size_t)255; };

    size_t n_tup = (size_t)2 * n_edges;
    size_t szT = n_tup * sizeof(uint2);                  // ~205 MB
    size_t szH = (size_t)NCH * nbins * sizeof(int);      // ~12.8 MB

    size_t off = 0;
    size_t oT  = off; off += align256(szT);
    size_t oCH = off; off += align256(szH);
    size_t oCO = off; off += align256(szH);
    size_t oCT = off; off += align256((size_t)nbins * sizeof(int));
    size_t oCB = off; off += align256((size_t)nbins * sizeof(int));
    bool ok = (off <= ws_size) && (nbins <= MAXB) && (n_atoms < (1 << 18));

    if (ok) {
        uint2* tuples = (uint2*)(w + oT);
        int*   chist  = (int*)(w + oCH);
        int*   coffs  = (int*)(w + oCO);
        int*   ctot   = (int*)(w + oCT);
        int*   cbase  = (int*)(w + oCB);

        n_hist   <<<NCH, TB, 0, stream>>>(nbr, chist, n_edges, nbins);
        n_rowscan<<<nbins, NCH, 0, stream>>>(chist, coffs, ctot, nbins);
        n_bases  <<<1, 1024, 0, stream>>>(ctot, cbase, nbins);
        {
            dim3 g((nbins + 1023) / 1024, NCH);
            n_addbase<<<g, 1024, 0, stream>>>(coffs, cbase, nbins);
        }
        n_scatter<<<NCH, TB, 0, stream>>>(nbr, dist, coffs, tuples,
                                          n_edges, nbins);
        int ablocks = (nbins + 15) / 16;
        n_accum  <<<ablocks, 256, 0, stream>>>(tuples, charges, cbase, ctot,
                                               (float4*)d_out, nbins, n_atoms);
    } else {
        hipMemsetAsync(d_out, 0, (size_t)out_size * sizeof(float), stream);
        edge_scatter_agent<<<(n_edges + 255) / 256, 256, 0, stream>>>(
            charges, nbr, dist, (float*)d_out, n_edges);
    }
}